// Round 11
// baseline (115.004 us; speedup 1.0000x reference)
//
#include <hip/hip_runtime.h>
#include <math.h>

#define DDIM 2048
#define NE 64
#define TOPK 8
#define RB 16            // rows per block -> grid = 1024 = 4 blocks/CU
#define KSEG 512         // per-wave K segment (4 waves split K=2048)
#define NKT (KSEG / 32)  // 16 k-tiles of 32 per wave

typedef float f32x4 __attribute__((ext_vector_type(4)));
typedef short short8 __attribute__((ext_vector_type(8)));
typedef __bf16 bf16x8 __attribute__((ext_vector_type(8)));
typedef unsigned int uint;

// ---- truncation split: f = hi + mid + lo, residuals exact in fp32 ----
__device__ __forceinline__ void split3(float f, short& h, short& m, short& l) {
    uint u = __builtin_bit_cast(uint, f);
    h = (short)(u >> 16);
    float r = f - __builtin_bit_cast(float, u & 0xffff0000u);
    uint ur = __builtin_bit_cast(uint, r);
    m = (short)(ur >> 16);
    float r2 = r - __builtin_bit_cast(float, ur & 0xffff0000u);
    l = (short)(__builtin_bit_cast(uint, r2) >> 16);
}

// ---- setup: w [64][2048] fp32 -> 3 bf16 planes in d_ws ----
__global__ void wsplit_kernel(const float* __restrict__ w, short* __restrict__ wh,
                              short* __restrict__ wm, short* __restrict__ wl) {
    int tid = blockIdx.x * 256 + threadIdx.x;
    size_t base = (size_t)tid * 8;
    short8 hs, ms, ls;
#pragma unroll
    for (int j = 0; j < 8; ++j) {
        short h, m, l;
        split3(w[base + j], h, m, l);
        hs[j] = h; ms[j] = m; ls[j] = l;
    }
    *(short8*)&wh[base] = hs;
    *(short8*)&wm[base] = ms;
    *(short8*)&wl[base] = ls;
}

__global__ __launch_bounds__(256, 2) void gate_kernel(
    const float* __restrict__ x,      // [NR, D]
    const float* __restrict__ bias,   // [E]
    const short* __restrict__ wh,     // [E, D] bf16 planes
    const short* __restrict__ wm,
    const short* __restrict__ wl,
    float* __restrict__ out_w,        // [NR, K]
    float* __restrict__ out_i)        // [NR, K] indices as float
{
    __shared__ float slab[4][RB][NE + 2];  // pitch 66: conflict-free partial writes
    __shared__ float logits[RB][NE + 1];

    const int t    = threadIdx.x;
    const int lane = t & 63;
    const int wv   = t >> 6;          // wave = k-quarter
    const int rl   = lane & 15;       // row-in-tile (A) / col (B,C)
    const int kg   = lane >> 4;       // k-group 0..3
    const int row0 = blockIdx.x * RB;
    const int kbase = wv * KSEG;

    f32x4 acc[4];                     // [expert-tile], 16 VGPR
#pragma unroll
    for (int et = 0; et < 4; ++et) acc[et] = (f32x4){0.f, 0.f, 0.f, 0.f};

    const float* xb  = x  + (size_t)(row0 + rl) * DDIM + kbase + kg * 8;
    const short* whb = wh + (size_t)rl * DDIM + kbase + kg * 8;
    const short* wmb = wm + (size_t)rl * DDIM + kbase + kg * 8;
    const short* wlb = wl + (size_t)rl * DDIM + kbase + kg * 8;

    // two named register tile-sets (A/B) -> barrier-free software pipeline
    f32x4 Aa0, Aa1, Ba0, Ba1;
    short8 Abh[4], Abm[4], Abl[4], Bbh[4], Bbm[4], Bbl[4];

#define LOADT(P, ko_)                                                          \
    {                                                                          \
        P##a0 = *(const f32x4*)(xb + (ko_));                                   \
        P##a1 = *(const f32x4*)(xb + (ko_) + 4);                               \
        _Pragma("unroll")                                                      \
        for (int et = 0; et < 4; ++et) {                                       \
            P##bh[et] = *(const short8*)&whb[et * 16 * DDIM + (ko_)];          \
            P##bm[et] = *(const short8*)&wmb[et * 16 * DDIM + (ko_)];          \
            P##bl[et] = *(const short8*)&wlb[et * 16 * DDIM + (ko_)];          \
        }                                                                      \
    }

#define COMPUTE(P)                                                             \
    {                                                                          \
        short8 hs, ms, ls;                                                     \
        _Pragma("unroll")                                                      \
        for (int j = 0; j < 4; ++j) {                                          \
            short h_, m_, l_;                                                  \
            split3(P##a0[j], h_, m_, l_); hs[j] = h_; ms[j] = m_; ls[j] = l_;  \
            split3(P##a1[j], h_, m_, l_); hs[j+4] = h_; ms[j+4] = m_; ls[j+4] = l_; \
        }                                                                      \
        bf16x8 ah = __builtin_bit_cast(bf16x8, hs);                            \
        bf16x8 am = __builtin_bit_cast(bf16x8, ms);                            \
        bf16x8 al = __builtin_bit_cast(bf16x8, ls);                            \
        _Pragma("unroll")                                                      \
        for (int et = 0; et < 4; ++et) {                                       \
            bf16x8 bh = __builtin_bit_cast(bf16x8, P##bh[et]);                 \
            bf16x8 bm = __builtin_bit_cast(bf16x8, P##bm[et]);                 \
            bf16x8 bl = __builtin_bit_cast(bf16x8, P##bl[et]);                 \
            acc[et] = __builtin_amdgcn_mfma_f32_16x16x32_bf16(ah, bh, acc[et], 0, 0, 0); \
            acc[et] = __builtin_amdgcn_mfma_f32_16x16x32_bf16(ah, bm, acc[et], 0, 0, 0); \
            acc[et] = __builtin_amdgcn_mfma_f32_16x16x32_bf16(am, bh, acc[et], 0, 0, 0); \
            acc[et] = __builtin_amdgcn_mfma_f32_16x16x32_bf16(am, bm, acc[et], 0, 0, 0); \
            acc[et] = __builtin_amdgcn_mfma_f32_16x16x32_bf16(ah, bl, acc[et], 0, 0, 0); \
            acc[et] = __builtin_amdgcn_mfma_f32_16x16x32_bf16(al, bh, acc[et], 0, 0, 0); \
        }                                                                      \
    }

    LOADT(A, 0);
    for (int kt = 0; kt < NKT; kt += 2) {
        LOADT(B, (kt + 1) * 32);          // in flight during COMPUTE(A)
        COMPUTE(A);
        if (kt + 2 < NKT) LOADT(A, (kt + 2) * 32);  // in flight during COMPUTE(B)
        COMPUTE(B);
    }

    // ---- k-quarter partials (C/D: row=kg*4+r, col=rl) ----
#pragma unroll
    for (int et = 0; et < 4; ++et)
#pragma unroll
        for (int r = 0; r < 4; ++r)
            slab[wv][kg * 4 + r][et * 16 + rl] = acc[et][r];
    __syncthreads();

    // ---- reduce 4 k-quarters -> logits (1024 entries / 256 thr) ----
#pragma unroll
    for (int i = 0; i < 4; ++i) {
        int idx = t * 4 + i;
        int r = idx >> 6, cc = idx & 63;
        logits[r][cc] = slab[0][r][cc] + slab[1][r][cc] + slab[2][r][cc] + slab[3][r][cc];
    }
    __syncthreads();

    // ---- top-8: 4 rows/wave, k outer, rows interleaved for shfl-chain ILP ----
    const float bias_l = bias[lane];
    float raw[4], sig[4], vv[4], wsum[4], myw[4];
    int myidx[4];
#pragma unroll
    for (int r = 0; r < 4; ++r) {
        raw[r] = logits[wv * 4 + r][lane];
        sig[r] = 1.f / (1.f + expf(-raw[r]));
        vv[r]  = raw[r] + bias_l;
        wsum[r] = 0.f; myw[r] = 0.f; myidx[r] = 0;
    }
#pragma unroll
    for (int k = 0; k < TOPK; ++k) {
        float m0[4];
#pragma unroll
        for (int r = 0; r < 4; ++r) m0[r] = vv[r];
#pragma unroll
        for (int off = 32; off; off >>= 1)
#pragma unroll
            for (int r = 0; r < 4; ++r)
                m0[r] = fmaxf(m0[r], __shfl_xor(m0[r], off));
#pragma unroll
        for (int r = 0; r < 4; ++r) {
            unsigned long long b = __ballot(vv[r] == m0[r]);
            int idx = (int)__builtin_ctzll(b);          // lowest index wins ties
            float wk = __shfl(sig[r], idx);
            wsum[r] += wk;                               // reference summation order
            if (lane == k)   { myw[r] = wk; myidx[r] = idx; }
            if (lane == idx) vv[r] = -INFINITY;
        }
    }
#pragma unroll
    for (int r = 0; r < 4; ++r) {
        if (lane < TOPK) {
            const int gr = row0 + wv * 4 + r;
            out_w[(size_t)gr * TOPK + lane] = myw[r] / wsum[r];
            out_i[(size_t)gr * TOPK + lane] = (float)myidx[r];
        }
    }
}

extern "C" void kernel_launch(void* const* d_in, const int* in_sizes, int n_in,
                              void* d_out, int out_size, void* d_ws, size_t ws_size,
                              hipStream_t stream) {
    const float* x    = (const float*)d_in[0];
    const float* w    = (const float*)d_in[1];
    const float* bias = (const float*)d_in[2];
    const int NR = in_sizes[0] / DDIM;          // 16384 rows
    float* out   = (float*)d_out;
    float* out_w = out;
    float* out_i = out + (size_t)NR * TOPK;

    short* wh = (short*)d_ws;                   // 3 x 256 KB bf16 planes
    short* wm = wh + (size_t)NE * DDIM;
    short* wl = wm + (size_t)NE * DDIM;

    hipLaunchKernelGGL(wsplit_kernel, dim3(NE * DDIM / (256 * 8)), dim3(256), 0, stream,
                       w, wh, wm, wl);
    hipLaunchKernelGGL(gate_kernel, dim3(NR / RB), dim3(256), 0, stream,
                       x, bias, wh, wm, wl, out_w, out_i);
}